// Round 12
// baseline (528.605 us; speedup 1.0000x reference)
//
#include <hip/hip_runtime.h>

// gcd(a,b)*W_gcd -> out[0..N), (a%p)*W_mod -> out[N..2N)
// a,b in [0,1e6), p in [1,1e6): all values < 2^20, nonnegative.
//
// MODEL (R11): all at-floor configs (R5/R10: 177-178us) satisfy
//   wall ~= hbm_bytes(448 MiB) / 2.6 TB/s; VALU-busy (~120us) hides under.
//   We are MEMORY-bound at an effective 2.6 TB/s, not VALU-bound — which is
//   why every compute-side change nulled. Hypothesis under test: the cap is
//   L3 capacity (384 MiB input vs 256 MiB L3, ~50% read-hit observed; the
//   256 MiB output stream ALLOCATES in L3 and evicts input lines).
// CHANGE: non-temporal output stores (nt flag) -> outputs don't allocate
//   in L2/L3, input retention rises, FETCH_SIZE drops. If FETCH drops but
//   wall doesn't, the cap is R/W turnaround -> practical roofline.
// GCD: Stein, 4-way interleaved, 4-inst step (v_ffbl/v_lshrrev/v_sad/v_min);
//   (0,g_odd) fixed point; fixed-16 straight-line then check-every-8.
// MOD: exact fp32 (ints < 2^20): q=rint(a*rcp(p)), r=fma(-q,p,a), 1 fixup.

typedef int   v4i __attribute__((ext_vector_type(4)));
typedef float v4f __attribute__((ext_vector_type(4)));

__device__ __forceinline__ unsigned ffbl(unsigned x) {
    unsigned r;
    asm("v_ffbl_b32 %0, %1" : "=v"(r) : "v"(x));   // -1 if x==0
    return r;
}

__global__ __launch_bounds__(256) void ntb_kernel(
    const v4i* __restrict__ a4, const v4i* __restrict__ b4,
    const v4i* __restrict__ p4,
    const float* __restrict__ Wg, const float* __restrict__ Wm,
    v4f* __restrict__ gcd_out, v4f* __restrict__ mod_out, int n4)
{
    const int i = blockIdx.x * blockDim.x + threadIdx.x;
    if (i >= n4) return;

    const float wg = Wg[0];
    const float wm = Wm[0];

    const v4i av = a4[i];
    const v4i bv = b4[i];
    const v4i pv = p4[i];

    // ---- mod branch first: NT store overlaps the GCD loop ----
    {
        v4f m;
        #pragma unroll
        for (int v = 0; v < 4; ++v) {
            const float af = (float)(unsigned)av[v];
            const float pf = (float)(unsigned)pv[v];
            const float q  = rintf(af * __builtin_amdgcn_rcpf(pf)); // {floor,floor+1}
            float r = fmaf(-q, pf, af);                             // exact, in (-p,p)
            r += (r < 0.0f) ? pf : 0.0f;
            m[v] = r * wm;
        }
        __builtin_nontemporal_store(m, mod_out + i);   // no L3 allocation
    }

    // ---- GCD ----
    unsigned A[4], B[4], S[4];
    #pragma unroll
    for (int v = 0; v < 4; ++v) {
        A[v] = (unsigned)av[v];
        B[v] = (unsigned)bv[v];
        S[v] = ffbl(A[v] | B[v]);            // &31 folds into the final shift
        A[v] >>= (ffbl(A[v]) & 31u);         // A=0 -> stays 0
    }

    // 16 fixed passes, straight-line, no checks (wave-max is always > 16).
    #pragma unroll
    for (int it = 0; it < 16; ++it) {
        #pragma unroll
        for (int v = 0; v < 4; ++v) {
            const unsigned b  = B[v] >> (ffbl(B[v]) & 31u); // 0 -> 0
            const unsigned nb = __usad(A[v], b, 0u);        // |A - b|
            A[v] = min(A[v], b);
            B[v] = nb;
        }
    }

    // Cleanup: check first, then 8 passes at a time (typically 1-2 rounds).
    while (__any((A[0] | A[1] | A[2] | A[3]) != 0u)) {
        #pragma unroll
        for (int it = 0; it < 8; ++it) {
            #pragma unroll
            for (int v = 0; v < 4; ++v) {
                const unsigned b  = B[v] >> (ffbl(B[v]) & 31u);
                const unsigned nb = __usad(A[v], b, 0u);
                A[v] = min(A[v], b);
                B[v] = nb;
            }
        }
    }

    v4f g;
    g[0] = (float)((A[0] | B[0]) << (S[0] & 31u)) * wg;
    g[1] = (float)((A[1] | B[1]) << (S[1] & 31u)) * wg;
    g[2] = (float)((A[2] | B[2]) << (S[2] & 31u)) * wg;
    g[3] = (float)((A[3] | B[3]) << (S[3] & 31u)) * wg;
    __builtin_nontemporal_store(g, gcd_out + i);       // no L3 allocation
}

extern "C" void kernel_launch(void* const* d_in, const int* in_sizes, int n_in,
                              void* d_out, int out_size, void* d_ws, size_t ws_size,
                              hipStream_t stream) {
    const int n  = in_sizes[0];   // 2^25
    const int n4 = n >> 2;        // 8,388,608 int4 groups

    const v4i* a4 = (const v4i*)d_in[0];
    const v4i* b4 = (const v4i*)d_in[1];
    const v4i* p4 = (const v4i*)d_in[2];
    const float* Wg = (const float*)d_in[3];
    const float* Wm = (const float*)d_in[4];

    float* out = (float*)d_out;
    v4f* gcd_out = (v4f*)out;        // first N floats
    v4f* mod_out = (v4f*)(out + n);  // second N floats

    const int block = 256;
    const int grid  = (n4 + block - 1) / block;  // 32768: one group per thread

    ntb_kernel<<<grid, block, 0, stream>>>(a4, b4, p4, Wg, Wm, gcd_out, mod_out, n4);
}